// Round 16
// baseline (291.833 us; speedup 1.0000x reference)
//
#include <hip/hip_runtime.h>
#include <hip/hip_bf16.h>
#include <math.h>

// STGCN, round 16: streaming pivot, GRID FIX.
// r15's 5-kernel barrier-free pipeline failed correctness from two grid
// off-by-ones: k3 needs 28,928 Mtiles -> 3616 blocks (was 3612) and k4 needs
// 904 blocks (was 903). 512 rows of stage4 were never computed -> stale
// h1c bytes flowed to the output (absmax 0.14). This round fixes ONLY those
// two launch constants; all kernels byte-identical to r15.
//   k1: x -> h1c   (stage1+cheb1, per-wave LDS bounce)   3616 blocks
//   k2: h1c -> h2  (stage3 + BN)                          2712 blocks
//   k3: h2 -> h3   (stage4, K=192)                        3616 blocks  [FIX]
//   k4: h3 -> h3c  (cheb2)                                 904 blocks  [FIX]
//   k5: h3c -> out (stage6 + mlp1 + mlp2)                  904 blocks
// Fallback to proven r11 fused kernel (138.7us) if ws too small.

namespace {

constexpr float INV_STD = 0.9999950000374997f; // 1/sqrt(1+1e-5)

typedef __attribute__((ext_vector_type(8))) short bf16x8;
typedef __attribute__((ext_vector_type(4))) float f32x4;

// ---- ws layout ----
constexpr int OFF_CHEB_A = 0;         // [32co][32k]
constexpr int OFF_CHEB_B = 1024;      // [32co][32k]
constexpr int OFF_A2     = 2048;      // P,Q,R x [64co][96k]
constexpr int OFF_B1     = 20480;     // P,Q,R x [32co][192k]
constexpr int OFF_B2     = 38912;     // P,Q,R x [16co][96k]
constexpr int OFF_S1B    = 43520;     // P,Q,R x [32co][32k] (zero-padded K)
constexpr int OFF_W1     = 46592;     // 113 x [64h][32k]
constexpr int OFF_W2     = 278016;    // 113 x [3o][64k]
// intermediates (bf16 elem offsets from ws base):
constexpr size_t E_A   = 524288;              // h1c (k3 reuses lower half as h3)
constexpr size_t E_H3C = 524288 + 14811136;   // h3c (upper half of dead h1c)
constexpr size_t E_H2  = 524288 + 29622272;   // h2
constexpr size_t NEED_BYTES = 149159936;

__device__ __forceinline__ unsigned short f2bf(float f){   // RNE f32->bf16
  unsigned int u = __float_as_uint(f);
  u += 0x7fffu + ((u >> 16) & 1u);
  return (unsigned short)(u >> 16);
}
__device__ __forceinline__ unsigned short f2bf_fast(float f){
  return __bfloat16_as_ushort(__float2bfloat16(f));
}
__device__ __forceinline__ f32x4 bcast(float v){ f32x4 r; r[0]=v; r[1]=v; r[2]=v; r[3]=v; return r; }

struct Params {
  const float *x;
  const float *awp,*abp,*awq,*abq,*awr,*abr,*acw,*acb;
  const float *awp2,*abp2,*awq2,*abq2,*awr2,*abr2,*ag,*abeta;
  const float *bwp,*bbp,*bwq,*bbq,*bwr,*bbr,*bcw,*bcb;
  const float *bwp2,*bbp2,*bwq2,*bbq2,*bwr2,*bbr2,*bg,*bbeta;
  const float *w1,*b1,*w2,*b2;
  float *out;
};

// ---------------- prep: one-time weight transpose/convert ----------------
__global__ void stgcn_prep(const Params p, unsigned short* __restrict__ W)
{
  int e = blockIdx.x*256 + threadIdx.x;
  if (e < 2048){
    const float* src = (e < 1024) ? p.acw : p.bcw;
    const int j = e & 1023, co = j >> 5, k = j & 31;
    W[e] = f2bf(src[k*32 + co]);
    return;
  }
  e -= 2048;
  if (e < 18432){
    const int mat = e / 6144, j = e % 6144, co = j / 96, k = j % 96;
    const float* src = mat==0 ? p.awp2 : (mat==1 ? p.awq2 : p.awr2);
    W[OFF_A2 + e] = f2bf(src[k*64 + co]);
    return;
  }
  e -= 18432;
  if (e < 18432){
    const int mat = e / 6144, j = e % 6144, co = j / 192, k = j % 192;
    const float* src = mat==0 ? p.bwp : (mat==1 ? p.bwq : p.bwr);
    W[OFF_B1 + e] = f2bf(src[k*32 + co]);
    return;
  }
  e -= 18432;
  if (e < 4608){
    const int mat = e / 1536, j = e % 1536, co = j / 96, k = j % 96;
    const float* src = mat==0 ? p.bwp2 : (mat==1 ? p.bwq2 : p.bwr2);
    W[OFF_B2 + e] = f2bf(src[k*16 + co]);
    return;
  }
  e -= 4608;
  if (e < 3072){
    const int mat = e / 1024, j = e % 1024, co = j >> 5, k = j & 31;
    const int tt = k >> 3, ci = k & 7;
    const float* src = mat==0 ? p.awp : (mat==1 ? p.awq : p.awr);
    W[OFF_S1B + e] = (ci < 4 && tt < 3) ? f2bf(src[(tt*4+ci)*32 + co])
                                        : (unsigned short)0;
    return;
  }
  e -= 3072;
  if (e < 231424){ W[OFF_W1 + e] = f2bf(p.w1[e]); return; }
  e -= 231424;
  if (e < 21696){ W[OFF_W2 + e] = f2bf(p.w2[e]); }
}

// ================= streaming path (no block barriers) =================

// ---- k1: x -> h1c. wave = 2 Mtiles (32 rows = 4 pairs x 8t), per-wave LDS bounce.
__global__ __launch_bounds__(512, 4) void k1_front(const Params p,
    const unsigned short* __restrict__ W, unsigned short* __restrict__ H1C)
{
  __shared__ unsigned short h1L[8192];
  const int tid = threadIdx.x, l = tid & 63, wid = tid >> 6;
  const int lm = l & 15, lk = l >> 4;
  unsigned short* hl = h1L + wid*1024;
  const int Mt0 = (blockIdx.x*8 + wid) * 2;

  bf16x8 av[2];
  #pragma unroll
  for (int mt = 0; mt < 2; ++mt){
    const int m = (Mt0+mt)*16 + lm;
    const int pair = m >> 3, t = m & 7;
    const int nn = pair >> 10, b = pair & 1023;
    bf16x8 a;
    #pragma unroll
    for (int j = 0; j < 8; ++j) a[j] = 0;
    if (lk < 3){
      const float4 xf = *reinterpret_cast<const float4*>(
          &p.x[(size_t)((b*10 + t + lk)*113 + nn)*4]);
      a[0]=(short)f2bf(xf.x); a[1]=(short)f2bf(xf.y);
      a[2]=(short)f2bf(xf.z); a[3]=(short)f2bf(xf.w);
    }
    av[mt] = a;
  }
  #pragma unroll
  for (int Nt = 0; Nt < 2; ++Nt){
    const unsigned short* wb = W + OFF_S1B + (Nt*16+lm)*32 + lk*8;
    const bf16x8 wp = *reinterpret_cast<const bf16x8*>(wb);
    const bf16x8 wq = *reinterpret_cast<const bf16x8*>(wb + 1024);
    const bf16x8 wr = *reinterpret_cast<const bf16x8*>(wb + 2048);
    const int cb = Nt*16 + lk*4;
    const f32x4 b0 = *reinterpret_cast<const f32x4*>(p.abp + cb);
    const f32x4 b1 = *reinterpret_cast<const f32x4*>(p.abq + cb);
    const f32x4 b2 = *reinterpret_cast<const f32x4*>(p.abr + cb);
    #pragma unroll
    for (int mt = 0; mt < 2; ++mt){
      f32x4 aP = b0, aQ = b1, aR = b2;
      aP = __builtin_amdgcn_mfma_f32_16x16x32_bf16(wp, av[mt], aP, 0,0,0);
      aQ = __builtin_amdgcn_mfma_f32_16x16x32_bf16(wq, av[mt], aQ, 0,0,0);
      aR = __builtin_amdgcn_mfma_f32_16x16x32_bf16(wr, av[mt], aR, 0,0,0);
      unsigned short pv[4];
      #pragma unroll
      for (int r = 0; r < 4; ++r){
        const float sig = 1.f/(1.f + __expf(-aQ[r]));
        pv[r] = f2bf_fast(fmaxf(fmaf(aP[r], sig, aR[r]), 0.f));
      }
      ushort4 pk; pk.x=pv[0]; pk.y=pv[1]; pk.z=pv[2]; pk.w=pv[3];
      *reinterpret_cast<ushort4*>(hl + (mt*16+lm)*32 + cb) = pk;
    }
  }
  bf16x8 bv[2];
  #pragma unroll
  for (int mt = 0; mt < 2; ++mt)
    bv[mt] = *reinterpret_cast<const bf16x8*>(hl + (mt*16+lm)*32 + lk*8);
  #pragma unroll
  for (int Nt = 0; Nt < 2; ++Nt){
    const bf16x8 wc = *reinterpret_cast<const bf16x8*>(
        W + OFF_CHEB_A + (Nt*16+lm)*32 + lk*8);
    const int cb = Nt*16 + lk*4;
    const f32x4 b0 = *reinterpret_cast<const f32x4*>(p.acb + cb);
    #pragma unroll
    for (int mt = 0; mt < 2; ++mt){
      f32x4 acc = b0;
      acc = __builtin_amdgcn_mfma_f32_16x16x32_bf16(wc, bv[mt], acc, 0,0,0);
      const int m = (Mt0+mt)*16 + lm;
      const int pair = m >> 3, t = m & 7;
      unsigned short pv[4];
      #pragma unroll
      for (int r = 0; r < 4; ++r) pv[r] = f2bf_fast(fmaxf(acc[r], 0.f));
      ushort4 pk; pk.x=pv[0]; pk.y=pv[1]; pk.z=pv[2]; pk.w=pv[3];
      *reinterpret_cast<ushort4*>(H1C + (size_t)pair*256 + t*32 + cb) = pk;
    }
  }
}

// ---- k2: h1c -> h2 (stage3 gated conv + BN(a)). wave = 2 Mtiles x 4 Ntiles.
__global__ __launch_bounds__(512, 4) void k2_s3(const Params p,
    const unsigned short* __restrict__ W, const unsigned short* __restrict__ H1C,
    unsigned short* __restrict__ H2)
{
  const int tid = threadIdx.x, l = tid & 63, wid = tid >> 6;
  const int lm = l & 15, lk = l >> 4;
  const int Mt0 = (blockIdx.x*8 + wid) * 2;

  bf16x8 av[2][3];
  int prs[2], ts[2];
  #pragma unroll
  for (int mt = 0; mt < 2; ++mt){
    const int m = (Mt0+mt)*16 + lm;
    const int pair = m / 6, t = m - pair*6;
    prs[mt] = pair; ts[mt] = t;
    const unsigned short* ab = H1C + (size_t)pair*256 + t*32 + lk*8;
    #pragma unroll
    for (int ks = 0; ks < 3; ++ks)
      av[mt][ks] = *reinterpret_cast<const bf16x8*>(ab + ks*32);
  }
  #pragma unroll
  for (int Nt = 0; Nt < 4; ++Nt){
    const unsigned short* wb = W + OFF_A2 + (Nt*16+lm)*96 + lk*8;
    bf16x8 wp[3], wq[3], wr[3];
    #pragma unroll
    for (int ks = 0; ks < 3; ++ks){
      wp[ks] = *reinterpret_cast<const bf16x8*>(wb + ks*32);
      wq[ks] = *reinterpret_cast<const bf16x8*>(wb +  6144 + ks*32);
      wr[ks] = *reinterpret_cast<const bf16x8*>(wb + 12288 + ks*32);
    }
    const int cb = Nt*16 + lk*4;
    const f32x4 b0 = *reinterpret_cast<const f32x4*>(p.abp2 + cb);
    const f32x4 b1 = *reinterpret_cast<const f32x4*>(p.abq2 + cb);
    const f32x4 b2 = *reinterpret_cast<const f32x4*>(p.abr2 + cb);
    #pragma unroll
    for (int mt = 0; mt < 2; ++mt){
      f32x4 aP = b0, aQ = b1, aR = b2;
      #pragma unroll
      for (int ks = 0; ks < 3; ++ks){
        aP = __builtin_amdgcn_mfma_f32_16x16x32_bf16(wp[ks], av[mt][ks], aP, 0,0,0);
        aQ = __builtin_amdgcn_mfma_f32_16x16x32_bf16(wq[ks], av[mt][ks], aQ, 0,0,0);
        aR = __builtin_amdgcn_mfma_f32_16x16x32_bf16(wr[ks], av[mt][ks], aR, 0,0,0);
      }
      const int pair = prs[mt], nn = pair >> 10;
      const float bns = INV_STD * p.ag[nn], bnb = p.abeta[nn];
      unsigned short pv[4];
      #pragma unroll
      for (int r = 0; r < 4; ++r){
        const float sig = 1.f/(1.f + __expf(-aQ[r]));
        float v = fmaxf(fmaf(aP[r], sig, aR[r]), 0.f);
        v = fmaxf(fmaf(v, bns, bnb), 0.f);
        pv[r] = f2bf_fast(v);
      }
      ushort4 pk; pk.x=pv[0]; pk.y=pv[1]; pk.z=pv[2]; pk.w=pv[3];
      *reinterpret_cast<ushort4*>(H2 + (size_t)pair*384 + ts[mt]*64 + cb) = pk;
    }
  }
}

// ---- k3: h2 -> h3 (stage4 gated conv, K=192). wave = 1 Mtile x 2 Ntiles.
__global__ __launch_bounds__(512, 4) void k3_s4(const Params p,
    const unsigned short* __restrict__ W, const unsigned short* __restrict__ H2,
    unsigned short* __restrict__ H3)
{
  const int tid = threadIdx.x, l = tid & 63, wid = tid >> 6;
  const int lm = l & 15, lk = l >> 4;
  const int Mt = blockIdx.x*8 + wid;
  const int m = Mt*16 + lm;
  const int pair = m >> 2, t = m & 3;

  bf16x8 av[6];
  {
    const unsigned short* ab = H2 + (size_t)pair*384 + lk*8;
    #pragma unroll
    for (int ks = 0; ks < 6; ++ks)
      av[ks] = *reinterpret_cast<const bf16x8*>(ab + (t + (ks>>1))*64 + (ks&1)*32);
  }
  #pragma unroll
  for (int Nt = 0; Nt < 2; ++Nt){
    const unsigned short* wb = W + OFF_B1 + (Nt*16+lm)*192 + lk*8;
    const int cb = Nt*16 + lk*4;
    f32x4 aP = *reinterpret_cast<const f32x4*>(p.bbp + cb);
    f32x4 aQ = *reinterpret_cast<const f32x4*>(p.bbq + cb);
    f32x4 aR = *reinterpret_cast<const f32x4*>(p.bbr + cb);
    #pragma unroll
    for (int kb = 0; kb < 2; ++kb){
      bf16x8 wp[3], wq[3], wr[3];
      #pragma unroll
      for (int s = 0; s < 3; ++s){
        const int ks = kb*3 + s;
        wp[s] = *reinterpret_cast<const bf16x8*>(wb +         ks*32);
        wq[s] = *reinterpret_cast<const bf16x8*>(wb +  6144 + ks*32);
        wr[s] = *reinterpret_cast<const bf16x8*>(wb + 12288 + ks*32);
      }
      #pragma unroll
      for (int s = 0; s < 3; ++s){
        const int ks = kb*3 + s;
        aP = __builtin_amdgcn_mfma_f32_16x16x32_bf16(wp[s], av[ks], aP, 0,0,0);
        aQ = __builtin_amdgcn_mfma_f32_16x16x32_bf16(wq[s], av[ks], aQ, 0,0,0);
        aR = __builtin_amdgcn_mfma_f32_16x16x32_bf16(wr[s], av[ks], aR, 0,0,0);
      }
    }
    unsigned short pv[4];
    #pragma unroll
    for (int r = 0; r < 4; ++r){
      const float sig = 1.f/(1.f + __expf(-aQ[r]));
      pv[r] = f2bf_fast(fmaxf(fmaf(aP[r], sig, aR[r]), 0.f));
    }
    ushort4 pk; pk.x=pv[0]; pk.y=pv[1]; pk.z=pv[2]; pk.w=pv[3];
    *reinterpret_cast<ushort4*>(H3 + (size_t)pair*128 + t*32 + cb) = pk;
  }
}

// ---- k4: h3 -> h3c (cheb2). wave = 4 Mtiles x 2 Ntiles.
__global__ __launch_bounds__(512, 4) void k4_cheb2(const Params p,
    const unsigned short* __restrict__ W, const unsigned short* __restrict__ H3,
    unsigned short* __restrict__ H3C)
{
  const int tid = threadIdx.x, l = tid & 63, wid = tid >> 6;
  const int lm = l & 15, lk = l >> 4;
  const int Mt0 = (blockIdx.x*8 + wid) * 4;

  bf16x8 av[4];
  int prs[4], ts[4];
  #pragma unroll
  for (int mt = 0; mt < 4; ++mt){
    const int m = (Mt0+mt)*16 + lm;
    const int pair = m >> 2, t = m & 3;
    prs[mt] = pair; ts[mt] = t;
    av[mt] = *reinterpret_cast<const bf16x8*>(H3 + (size_t)pair*128 + t*32 + lk*8);
  }
  #pragma unroll
  for (int Nt = 0; Nt < 2; ++Nt){
    const bf16x8 wc = *reinterpret_cast<const bf16x8*>(
        W + OFF_CHEB_B + (Nt*16+lm)*32 + lk*8);
    const int cb = Nt*16 + lk*4;
    const f32x4 b0 = *reinterpret_cast<const f32x4*>(p.bcb + cb);
    #pragma unroll
    for (int mt = 0; mt < 4; ++mt){
      f32x4 acc = b0;
      acc = __builtin_amdgcn_mfma_f32_16x16x32_bf16(wc, av[mt], acc, 0,0,0);
      unsigned short pv[4];
      #pragma unroll
      for (int r = 0; r < 4; ++r) pv[r] = f2bf_fast(fmaxf(acc[r], 0.f));
      ushort4 pk; pk.x=pv[0]; pk.y=pv[1]; pk.z=pv[2]; pk.w=pv[3];
      *reinterpret_cast<ushort4*>(H3C + (size_t)prs[mt]*128 + ts[mt]*32 + cb) = pk;
    }
  }
}

// ---- k5: h3c -> out (stage6 + mlp1 + mlp2). wave = 16 pairs (n-uniform).
__global__ __launch_bounds__(512, 4) void k5_tail(const Params p,
    const unsigned short* __restrict__ W, const unsigned short* __restrict__ H3C)
{
  __shared__ unsigned short sc[13312];
  const int tid = threadIdx.x, l = tid & 63, wid = tid >> 6;
  const int lm = l & 15, lk = l >> 4;
  const int P0 = (blockIdx.x*8 + wid) * 16;
  const int nn = P0 >> 10;
  unsigned short* h4L  = sc + wid*1664;
  unsigned short* hidL = h4L + 512;

  {
    const unsigned short* wb = W + OFF_B2 + lm*96 + lk*8;
    bf16x8 wp[3], wq[3], wr[3];
    #pragma unroll
    for (int ks = 0; ks < 3; ++ks){
      wp[ks] = *reinterpret_cast<const bf16x8*>(wb +        ks*32);
      wq[ks] = *reinterpret_cast<const bf16x8*>(wb + 1536 + ks*32);
      wr[ks] = *reinterpret_cast<const bf16x8*>(wb + 3072 + ks*32);
    }
    const int cb = lk*4;
    const f32x4 b0 = *reinterpret_cast<const f32x4*>(p.bbp2 + cb);
    const f32x4 b1 = *reinterpret_cast<const f32x4*>(p.bbq2 + cb);
    const f32x4 b2 = *reinterpret_cast<const f32x4*>(p.bbr2 + cb);
    const float bns = INV_STD * p.bg[nn], bnb = p.bbeta[nn];
    #pragma unroll
    for (int mt = 0; mt < 2; ++mt){
      const int ml = mt*16 + lm;
      const int pl = ml >> 1, t = ml & 1;
      const unsigned short* ab = H3C + (size_t)(P0 + pl)*128 + t*32 + lk*8;
      f32x4 aP = b0, aQ = b1, aR = b2;
      #pragma unroll
      for (int ks = 0; ks < 3; ++ks){
        const bf16x8 a = *reinterpret_cast<const bf16x8*>(ab + ks*32);
        aP = __builtin_amdgcn_mfma_f32_16x16x32_bf16(wp[ks], a, aP, 0,0,0);
        aQ = __builtin_amdgcn_mfma_f32_16x16x32_bf16(wq[ks], a, aQ, 0,0,0);
        aR = __builtin_amdgcn_mfma_f32_16x16x32_bf16(wr[ks], a, aR, 0,0,0);
      }
      unsigned short pv[4];
      #pragma unroll
      for (int r = 0; r < 4; ++r){
        const float sig = 1.f/(1.f + __expf(-aQ[r]));
        float v = fmaxf(fmaf(aP[r], sig, aR[r]), 0.f);
        v = fmaxf(fmaf(v, bns, bnb), 0.f);
        pv[r] = f2bf_fast(v);
      }
      ushort4 pk; pk.x=pv[0]; pk.y=pv[1]; pk.z=pv[2]; pk.w=pv[3];
      *reinterpret_cast<ushort4*>(h4L + pl*32 + t*16 + cb) = pk;
    }
  }
  {
    const bf16x8 bh = *reinterpret_cast<const bf16x8*>(h4L + lm*32 + lk*8);
    #pragma unroll
    for (int Nt = 0; Nt < 4; ++Nt){
      const bf16x8 wf = *reinterpret_cast<const bf16x8*>(
          W + OFF_W1 + nn*2048 + (Nt*16+lm)*32 + lk*8);
      const int cb = Nt*16 + lk*4;
      f32x4 acc = *reinterpret_cast<const f32x4*>(p.b1 + nn*64 + cb);
      acc = __builtin_amdgcn_mfma_f32_16x16x32_bf16(wf, bh, acc, 0,0,0);
      unsigned short pv[4];
      #pragma unroll
      for (int r = 0; r < 4; ++r) pv[r] = f2bf_fast(fmaxf(acc[r], 0.f));
      ushort4 pk; pk.x=pv[0]; pk.y=pv[1]; pk.z=pv[2]; pk.w=pv[3];
      *reinterpret_cast<ushort4*>(hidL + lm*72 + cb) = pk;
    }
  }
  {
    const unsigned short* WM2 = W + OFF_W2 + nn*192;
    const int lmo = (lm < 3) ? lm : 0;
    f32x4 acc = bcast(0.f);
    if (lk == 0){ acc[0]=p.b2[nn*3]; acc[1]=p.b2[nn*3+1]; acc[2]=p.b2[nn*3+2]; }
    #pragma unroll
    for (int ks = 0; ks < 2; ++ks){
      const bf16x8 aw = *reinterpret_cast<const bf16x8*>(WM2 + lmo*64 + ks*32 + lk*8);
      const bf16x8 bh = *reinterpret_cast<const bf16x8*>(hidL + lm*72 + ks*32 + lk*8);
      acc = __builtin_amdgcn_mfma_f32_16x16x32_bf16(aw, bh, acc, 0,0,0);
    }
    if (lk == 0){
      const int pair = P0 + lm;
      const int b = pair & 1023;
      float* op = p.out + ((size_t)b*113 + nn)*3;
      op[0] = acc[0]; op[1] = acc[1]; op[2] = acc[2];
    }
  }
}

// ================= fallback: r11 fused kernel (138.7us, proven) =================

template<int TOUT, int CIN, int COUT, int NK, int RSTI, int PSTI, int RSTO, int PSTO,
         int KP, int EPI, int MJOBS, int MSTEP, bool RELOADB>
__device__ __forceinline__ void mfma_stage(const unsigned short* __restrict__ aB,
    const unsigned short* __restrict__ gW, unsigned short* __restrict__ oB,
    const float* __restrict__ gb0, const float* __restrict__ gb1,
    const float* __restrict__ gb2,
    const int Mtile0, const int Ntile, const int lm, const int lk,
    const float bnsc, const float bnbt)
{
  const unsigned short* wbase = gW + (Ntile*16 + lm)*KP + lk*8;
  const int colbase = Ntile*16 + lk*4;
  bf16x8 wp[NK], wq[NK], wr[NK];
  if constexpr (!RELOADB){
    #pragma unroll
    for (int ks = 0; ks < NK; ++ks){
      wp[ks] = *reinterpret_cast<const bf16x8*>(wbase + ks*32);
      if constexpr (EPI >= 1){
        wq[ks] = *reinterpret_cast<const bf16x8*>(wbase +   COUT*KP + ks*32);
        wr[ks] = *reinterpret_cast<const bf16x8*>(wbase + 2*COUT*KP + ks*32);
      }
    }
  }
  const f32x4 b0v = *reinterpret_cast<const f32x4*>(gb0 + colbase);
  f32x4 b1v, b2v;
  if constexpr (EPI >= 1){
    b1v = *reinterpret_cast<const f32x4*>(gb1 + colbase);
    b2v = *reinterpret_cast<const f32x4*>(gb2 + colbase);
  }
  #pragma unroll 1
  for (int j = 0; j < MJOBS; ++j){
    const int m  = (Mtile0 + j*MSTEP)*16 + lm;
    const int pr = m / TOUT;
    const int t  = m - pr*TOUT;
    f32x4 aP = b0v, aQ, aR;
    if constexpr (EPI >= 1){ aQ = b1v; aR = b2v; }
    #pragma unroll
    for (int ks = 0; ks < NK; ++ks){
      bf16x8 fp, fq, fr;
      if constexpr (RELOADB){
        fp = *reinterpret_cast<const bf16x8*>(wbase + ks*32);
        if constexpr (EPI >= 1){
          fq = *reinterpret_cast<const bf16x8*>(wbase +   COUT*KP + ks*32);
          fr = *reinterpret_cast<const bf16x8*>(wbase + 2*COUT*KP + ks*32);
        }
      } else {
        fp = wp[ks];
        if constexpr (EPI >= 1){ fq = wq[ks]; fr = wr[ks]; }
      }
      int elem;
      if constexpr (CIN == 32) elem = pr*PSTI + (t + ks)*RSTI + lk*8;
      else                     elem = pr*PSTI + (t + (ks>>1))*RSTI + (ks&1)*32 + lk*8;
      const bf16x8 a = *reinterpret_cast<const bf16x8*>(aB + elem);
      aP = __builtin_amdgcn_mfma_f32_16x16x32_bf16(fp, a, aP, 0, 0, 0);
      if constexpr (EPI >= 1){
        aQ = __builtin_amdgcn_mfma_f32_16x16x32_bf16(fq, a, aQ, 0, 0, 0);
        aR = __builtin_amdgcn_mfma_f32_16x16x32_bf16(fr, a, aR, 0, 0, 0);
      }
    }
    ushort4 pk;
    unsigned short pv[4];
    #pragma unroll
    for (int r = 0; r < 4; ++r){
      float v;
      if constexpr (EPI == 0) v = fmaxf(aP[r], 0.f);
      else {
        const float sig = 1.f/(1.f + __expf(-aQ[r]));
        v = fmaxf(fmaf(aP[r], sig, aR[r]), 0.f);
        if constexpr (EPI == 2) v = fmaxf(fmaf(v, bnsc, bnbt), 0.f);
      }
      pv[r] = f2bf_fast(v);
    }
    pk.x = pv[0]; pk.y = pv[1]; pk.z = pv[2]; pk.w = pv[3];
    *reinterpret_cast<ushort4*>(oB + pr*PSTO + t*RSTO + colbase) = pk;
  }
}

__device__ __forceinline__ void mfma_stage4(const unsigned short* __restrict__ aB,
    const unsigned short* __restrict__ gW, unsigned short* __restrict__ oB,
    const float* __restrict__ gb0, const float* __restrict__ gb1,
    const float* __restrict__ gb2,
    const int Mtile0, const int Ntile, const int lm, const int lk)
{
  const unsigned short* wbase = gW + (Ntile*16 + lm)*192 + lk*8;
  const int colbase = Ntile*16 + lk*4;
  f32x4 aP[2], aQ[2], aR[2];
  {
    const f32x4 b0v = *reinterpret_cast<const f32x4*>(gb0 + colbase);
    const f32x4 b1v = *reinterpret_cast<const f32x4*>(gb1 + colbase);
    const f32x4 b2v = *reinterpret_cast<const f32x4*>(gb2 + colbase);
    #pragma unroll
    for (int j=0;j<2;++j){ aP[j]=b0v; aQ[j]=b1v; aR[j]=b2v; }
  }
  #pragma unroll 1
  for (int kb = 0; kb < 2; ++kb){
    bf16x8 wp[3], wq[3], wr[3];
    #pragma unroll
    for (int s = 0; s < 3; ++s){
      const int ks = kb*3 + s;
      wp[s] = *reinterpret_cast<const bf16x8*>(wbase +         ks*32);
      wq[s] = *reinterpret_cast<const bf16x8*>(wbase +  6144 + ks*32);
      wr[s] = *reinterpret_cast<const bf16x8*>(wbase + 12288 + ks*32);
    }
    #pragma unroll
    for (int j = 0; j < 2; ++j){
      const int m  = (Mtile0 + j*4)*16 + lm;
      const int pr = m >> 2, t = m & 3;
      #pragma unroll
      for (int s = 0; s < 3; ++s){
        const int ks = kb*3 + s;
        const int elem = pr*432 + (t + (ks>>1))*72 + (ks&1)*32 + lk*8;
        const bf16x8 a = *reinterpret_cast<const bf16x8*>(aB + elem);
        aP[j] = __builtin_amdgcn_mfma_f32_16x16x32_bf16(wp[s], a, aP[j], 0,0,0);
        aQ[j] = __builtin_amdgcn_mfma_f32_16x16x32_bf16(wq[s], a, aQ[j], 0,0,0);
        aR[j] = __builtin_amdgcn_mfma_f32_16x16x32_bf16(wr[s], a, aR[j], 0,0,0);
      }
    }
  }
  #pragma unroll
  for (int j = 0; j < 2; ++j){
    const int m  = (Mtile0 + j*4)*16 + lm;
    const int pr = m >> 2, t = m & 3;
    ushort4 pk;
    unsigned short pv[4];
    #pragma unroll
    for (int r = 0; r < 4; ++r){
      const float sig = 1.f/(1.f + __expf(-aQ[j][r]));
      pv[r] = f2bf_fast(fmaxf(fmaf(aP[j][r], sig, aR[j][r]), 0.f));
    }
    pk.x = pv[0]; pk.y = pv[1]; pk.z = pv[2]; pk.w = pv[3];
    *reinterpret_cast<ushort4*>(oB + pr*160 + t*40 + colbase) = pk;
  }
}

__global__ __launch_bounds__(512, 4) void stgcn_main(const Params p,
    const unsigned short* __restrict__ W)
{
  __shared__ __align__(16) unsigned short smem[24064];
  unsigned short* const bufA = smem;
  unsigned short* const bufB = smem + 13824;
  unsigned short* const sxb  = bufB;

  const int tid = threadIdx.x;
  const int l   = tid & 63;
  const int wid = tid >> 6;
  const int lm  = l & 15;
  const int lk  = l >> 4;
  const int n   = blockIdx.x >> 5;
  const int b0  = (blockIdx.x & 31) * 32;

  for (int i = tid; i < 32*22; i += 512){
    const int pr = i / 22, c = i - pr*22;
    const int t  = c >> 1;
    unsigned short v0=0,v1=0,v2=0,v3=0;
    if (!(c & 1) && t < 10){
      const float4 xf = *reinterpret_cast<const float4*>(
          &p.x[(size_t)(((b0+pr)*10 + t)*113 + n)*4]);
      v0 = f2bf(xf.x); v1 = f2bf(xf.y); v2 = f2bf(xf.z); v3 = f2bf(xf.w);
    }
    ushort4 pk; pk.x=v0; pk.y=v1; pk.z=v2; pk.w=v3;
    *reinterpret_cast<ushort4*>(&sxb[i*4]) = pk;
  }
  __syncthreads();

  mfma_stage<8,32,32,1, 8,88, 40,320, 32, 1, 4,4, false>(
      sxb, W+OFF_S1B, bufA, p.abp, p.abq, p.abr, wid>>1, wid&1, lm, lk, 0.f, 0.f);
  __syncthreads();
  mfma_stage<8,32,32,1, 40,320, 40,320, 32, 0, 4,4, false>(
      bufA, W+OFF_CHEB_A, bufB, p.acb, p.acb, p.acb, wid>>1, wid&1, lm, lk, 0.f, 0.f);
  __syncthreads();
  {
    const float bnsc = INV_STD * p.ag[n], bnbt = p.abeta[n];
    mfma_stage<6,32,64,3, 40,320, 72,432, 96, 2, 6,2, true>(
        bufB, W+OFF_A2, bufA, p.abp2, p.abq2, p.abr2, wid>>2, wid&3, lm, lk, bnsc, bnbt);
  }
  __syncthreads();
  mfma_stage4(bufA, W+OFF_B1, bufB, p.bbp, p.bbq, p.bbr, wid>>1, wid&1, lm, lk);
  __syncthreads();
  mfma_stage<4,32,32,1, 40,160, 40,160, 32, 0, 2,4, false>(
      bufB, W+OFF_CHEB_B, bufA, p.bcb, p.bcb, p.bcb, wid>>1, wid&1, lm, lk, 0.f, 0.f);
  __syncthreads();
  if (wid < 4){
    const float bnsc = INV_STD * p.bg[n], bnbt = p.bbeta[n];
    mfma_stage<2,32,16,3, 40,160, 16,40, 96, 2, 1,1, false>(
        bufA, W+OFF_B2, bufB, p.bbp2, p.bbq2, p.bbr2, wid, 0, lm, lk, bnsc, bnbt);
  }
  __syncthreads();
  mfma_stage<1,32,64,1, 16,40, 16,72, 32, 0, 1,1, false>(
      bufB, W+OFF_W1 + n*2048, bufA, p.b1 + n*64, p.b1, p.b1, wid&1, wid>>1, lm, lk, 0.f, 0.f);
  __syncthreads();
  if (wid < 2){
    const unsigned short* WM2 = W + OFF_W2 + n*192;
    const int m = wid*16 + lm;
    const int lmo = (lm < 3) ? lm : 0;
    f32x4 acc = bcast(0.f);
    if (lk == 0){ acc[0]=p.b2[n*3]; acc[1]=p.b2[n*3+1]; acc[2]=p.b2[n*3+2]; }
    #pragma unroll
    for (int ks = 0; ks < 2; ++ks){
      const bf16x8 aw = *reinterpret_cast<const bf16x8*>(WM2 + lmo*64 + ks*32 + lk*8);
      const bf16x8 bh = *reinterpret_cast<const bf16x8*>(bufA + m*72 + ks*32 + lk*8);
      acc = __builtin_amdgcn_mfma_f32_16x16x32_bf16(aw, bh, acc, 0, 0, 0);
    }
    if (lk == 0){
      float* op = p.out + (size_t)((b0 + m)*113 + n)*3;
      op[0] = acc[0]; op[1] = acc[1]; op[2] = acc[2];
    }
  }
}

} // namespace

extern "C" void kernel_launch(void* const* d_in, const int* in_sizes, int n_in,
                              void* d_out, int out_size, void* d_ws, size_t ws_size,
                              hipStream_t stream) {
  (void)in_sizes; (void)n_in; (void)out_size;
  Params p;
  p.x     = (const float*)d_in[0];
  // d_in[1] = edge_index (unused: ChebConv K=1 keeps only the identity term)
  p.awp   = (const float*)d_in[2];  p.abp   = (const float*)d_in[3];
  p.awq   = (const float*)d_in[4];  p.abq   = (const float*)d_in[5];
  p.awr   = (const float*)d_in[6];  p.abr   = (const float*)d_in[7];
  p.acw   = (const float*)d_in[8];  p.acb   = (const float*)d_in[9];
  p.awp2  = (const float*)d_in[10]; p.abp2  = (const float*)d_in[11];
  p.awq2  = (const float*)d_in[12]; p.abq2  = (const float*)d_in[13];
  p.awr2  = (const float*)d_in[14]; p.abr2  = (const float*)d_in[15];
  p.ag    = (const float*)d_in[16]; p.abeta = (const float*)d_in[17];
  p.bwp   = (const float*)d_in[18]; p.bbp   = (const float*)d_in[19];
  p.bwq   = (const float*)d_in[20]; p.bbq   = (const float*)d_in[21];
  p.bwr   = (const float*)d_in[22]; p.bbr   = (const float*)d_in[23];
  p.bcw   = (const float*)d_in[24]; p.bcb   = (const float*)d_in[25];
  p.bwp2  = (const float*)d_in[26]; p.bbp2  = (const float*)d_in[27];
  p.bwq2  = (const float*)d_in[28]; p.bbq2  = (const float*)d_in[29];
  p.bwr2  = (const float*)d_in[30]; p.bbr2  = (const float*)d_in[31];
  p.bg    = (const float*)d_in[32]; p.bbeta = (const float*)d_in[33];
  p.w1    = (const float*)d_in[34]; p.b1    = (const float*)d_in[35];
  p.w2    = (const float*)d_in[36]; p.b2    = (const float*)d_in[37];
  p.out   = (float*)d_out;

  unsigned short* W = (unsigned short*)d_ws;

  stgcn_prep<<<1171, 256, 0, stream>>>(p, W);

  if (ws_size >= NEED_BYTES){
    unsigned short* H1C = W + E_A;     // [pair][8t][32], pair = n*1024+b
    unsigned short* H2  = W + E_H2;    // [pair][6t][64]
    unsigned short* H3  = W + E_A;     // [pair][4t][32] (reuses dead h1c, lower half)
    unsigned short* H3C = W + E_H3C;   // [pair][4t][32] (upper half)
    k1_front<<<3616, 512, 0, stream>>>(p, W, H1C);
    k2_s3   <<<2712, 512, 0, stream>>>(p, W, H1C, H2);
    k3_s4   <<<3616, 512, 0, stream>>>(p, W, H2, H3);    // FIX: 3612 -> 3616
    k4_cheb2<<< 904, 512, 0, stream>>>(p, W, H3, H3C);   // FIX:  903 ->  904
    k5_tail <<< 904, 512, 0, stream>>>(p, W, H3C);
  } else {
    stgcn_main<<<113*32, 512, 0, stream>>>(p, W);
  }
}

// Round 18
// 176.498 us; speedup vs baseline: 1.6535x; 1.6535x over previous
//
#include <hip/hip_runtime.h>
#include <hip/hip_bf16.h>
#include <math.h>

// STGCN fused, round 18: r17 (per-wave stage fusion) with the stage6
// addressing bug fixed. r17 used stage1-style k-indexing
// (t+(ks>>1))*40+(ks&1)*32 in the fused tail's s6 — reads row padding and
// skips the third conv tap -> absmax 2e37. Correct CIN=32 indexing is
// (t+ks)*40 + lk*8 (as in r11's stage6). Single-line fix; everything else
// identical to r17:
//  - s1+c1 fused per wave (private LDS bounce, no barrier)
//  - s6+mlp1+mlp2 fused per wave (4 pairs/wave, all 8 waves busy)
//  - barriers 8 -> 5; LDS 48,128B; s3/s4/c2 byte-identical to r11.

namespace {

constexpr int NT = 512;               // 8 waves
constexpr int NP = 32;                // (b,n) pairs per block (same n)
constexpr float INV_STD = 0.9999950000374997f; // 1/sqrt(1+1e-5)

typedef __attribute__((ext_vector_type(8))) short bf16x8;
typedef __attribute__((ext_vector_type(4))) float f32x4;

// d_ws layout (bf16 element offsets). All sections 16B-aligned (off%8==0).
constexpr int OFF_CHEB_A = 0;         // [32co][32k]
constexpr int OFF_CHEB_B = 1024;      // [32co][32k]
constexpr int OFF_A2     = 2048;      // P,Q,R x [64co][96k]
constexpr int OFF_B1     = 20480;     // P,Q,R x [32co][192k]
constexpr int OFF_B2     = 38912;     // P,Q,R x [16co][96k]
constexpr int OFF_S1B    = 43520;     // P,Q,R x [32co][32k] (zero-padded K)
constexpr int OFF_W1     = 46592;     // 113 x [64h][32k]
constexpr int OFF_W2     = 278016;    // 113 x [3o][64k]
// total ws bytes needed: (278016 + 21696) * 2 = 599,424

__device__ __forceinline__ unsigned short f2bf(float f){   // RNE f32->bf16 (prep)
  unsigned int u = __float_as_uint(f);
  u += 0x7fffu + ((u >> 16) & 1u);
  return (unsigned short)(u >> 16);
}
__device__ __forceinline__ unsigned short f2bf_fast(float f){  // native RNE
  return __bfloat16_as_ushort(__float2bfloat16(f));
}
__device__ __forceinline__ f32x4 bcast(float v){ f32x4 r; r[0]=v; r[1]=v; r[2]=v; r[3]=v; return r; }

struct Params {
  const float *x;
  const float *awp,*abp,*awq,*abq,*awr,*abr,*acw,*acb;
  const float *awp2,*abp2,*awq2,*abq2,*awr2,*abr2,*ag,*abeta;
  const float *bwp,*bbp,*bwq,*bbq,*bwr,*bbr,*bcw,*bcb;
  const float *bwp2,*bbp2,*bwq2,*bbq2,*bwr2,*bbr2,*bg,*bbeta;
  const float *w1,*b1,*w2,*b2;
  float *out;
};

// ---------------- prep: one-time weight transpose/convert into ws ----------------
__global__ void stgcn_prep(const Params p, unsigned short* __restrict__ W)
{
  int e = blockIdx.x*256 + threadIdx.x;
  if (e < 2048){                                    // cheb a/b [ci][co] -> [co][ci]
    const float* src = (e < 1024) ? p.acw : p.bcw;
    const int j = e & 1023, co = j >> 5, k = j & 31;
    W[e] = f2bf(src[k*32 + co]);
    return;
  }
  e -= 2048;
  if (e < 18432){                                   // a2: 3 x [64co][96k]
    const int mat = e / 6144, j = e % 6144, co = j / 96, k = j % 96;
    const float* src = mat==0 ? p.awp2 : (mat==1 ? p.awq2 : p.awr2);
    W[OFF_A2 + e] = f2bf(src[k*64 + co]);
    return;
  }
  e -= 18432;
  if (e < 18432){                                   // b1: 3 x [32co][192k]
    const int mat = e / 6144, j = e % 6144, co = j / 192, k = j % 192;
    const float* src = mat==0 ? p.bwp : (mat==1 ? p.bwq : p.bwr);
    W[OFF_B1 + e] = f2bf(src[k*32 + co]);
    return;
  }
  e -= 18432;
  if (e < 4608){                                    // b2: 3 x [16co][96k]
    const int mat = e / 1536, j = e % 1536, co = j / 96, k = j % 96;
    const float* src = mat==0 ? p.bwp2 : (mat==1 ? p.bwq2 : p.bwr2);
    W[OFF_B2 + e] = f2bf(src[k*16 + co]);
    return;
  }
  e -= 4608;
  if (e < 3072){                                    // s1: 3 x [32co][32k], k=tt*8+ci
    const int mat = e / 1024, j = e % 1024, co = j >> 5, k = j & 31;
    const int tt = k >> 3, ci = k & 7;
    const float* src = mat==0 ? p.awp : (mat==1 ? p.awq : p.awr);
    W[OFF_S1B + e] = (ci < 4 && tt < 3) ? f2bf(src[(tt*4+ci)*32 + co])
                                        : (unsigned short)0;
    return;
  }
  e -= 3072;
  if (e < 231424){ W[OFF_W1 + e] = f2bf(p.w1[e]); return; }  // [n][h][f] already B^T
  e -= 231424;
  if (e < 21696){ W[OFF_W2 + e] = f2bf(p.w2[e]); }           // [n][o][k] already B^T
}

// ---------------- generic MFMA stage (operand-swapped, r11) ----------------
template<int TOUT, int CIN, int COUT, int NK, int RSTI, int PSTI, int RSTO, int PSTO,
         int KP, int EPI, int MJOBS, int MSTEP, bool RELOADB>
__device__ __forceinline__ void mfma_stage(const unsigned short* __restrict__ aB,
    const unsigned short* __restrict__ gW, unsigned short* __restrict__ oB,
    const float* __restrict__ gb0, const float* __restrict__ gb1,
    const float* __restrict__ gb2,
    const int Mtile0, const int Ntile, const int lm, const int lk,
    const float bnsc, const float bnbt)
{
  const unsigned short* wbase = gW + (Ntile*16 + lm)*KP + lk*8;
  const int colbase = Ntile*16 + lk*4;
  bf16x8 wp[NK], wq[NK], wr[NK];
  if constexpr (!RELOADB){
    #pragma unroll
    for (int ks = 0; ks < NK; ++ks){
      wp[ks] = *reinterpret_cast<const bf16x8*>(wbase + ks*32);
      if constexpr (EPI >= 1){
        wq[ks] = *reinterpret_cast<const bf16x8*>(wbase +   COUT*KP + ks*32);
        wr[ks] = *reinterpret_cast<const bf16x8*>(wbase + 2*COUT*KP + ks*32);
      }
    }
  }
  const f32x4 b0v = *reinterpret_cast<const f32x4*>(gb0 + colbase);
  f32x4 b1v, b2v;
  if constexpr (EPI >= 1){
    b1v = *reinterpret_cast<const f32x4*>(gb1 + colbase);
    b2v = *reinterpret_cast<const f32x4*>(gb2 + colbase);
  }
  #pragma unroll 1
  for (int j = 0; j < MJOBS; ++j){
    const int m  = (Mtile0 + j*MSTEP)*16 + lm;
    const int pr = m / TOUT;
    const int t  = m - pr*TOUT;
    f32x4 aP = b0v, aQ, aR;
    if constexpr (EPI >= 1){ aQ = b1v; aR = b2v; }
    #pragma unroll
    for (int ks = 0; ks < NK; ++ks){
      bf16x8 fp, fq, fr;
      if constexpr (RELOADB){
        fp = *reinterpret_cast<const bf16x8*>(wbase + ks*32);
        if constexpr (EPI >= 1){
          fq = *reinterpret_cast<const bf16x8*>(wbase +   COUT*KP + ks*32);
          fr = *reinterpret_cast<const bf16x8*>(wbase + 2*COUT*KP + ks*32);
        }
      } else {
        fp = wp[ks];
        if constexpr (EPI >= 1){ fq = wq[ks]; fr = wr[ks]; }
      }
      int elem;
      if constexpr (CIN == 32) elem = pr*PSTI + (t + ks)*RSTI + lk*8;
      else                     elem = pr*PSTI + (t + (ks>>1))*RSTI + (ks&1)*32 + lk*8;
      const bf16x8 a = *reinterpret_cast<const bf16x8*>(aB + elem);
      aP = __builtin_amdgcn_mfma_f32_16x16x32_bf16(fp, a, aP, 0, 0, 0);
      if constexpr (EPI >= 1){
        aQ = __builtin_amdgcn_mfma_f32_16x16x32_bf16(fq, a, aQ, 0, 0, 0);
        aR = __builtin_amdgcn_mfma_f32_16x16x32_bf16(fr, a, aR, 0, 0, 0);
      }
    }
    ushort4 pk;
    unsigned short pv[4];
    #pragma unroll
    for (int r = 0; r < 4; ++r){
      float v;
      if constexpr (EPI == 0) v = fmaxf(aP[r], 0.f);
      else {
        const float sig = 1.f/(1.f + __expf(-aQ[r]));
        v = fmaxf(fmaf(aP[r], sig, aR[r]), 0.f);
        if constexpr (EPI == 2) v = fmaxf(fmaf(v, bnsc, bnbt), 0.f);
      }
      pv[r] = f2bf_fast(v);
    }
    pk.x = pv[0]; pk.y = pv[1]; pk.z = pv[2]; pk.w = pv[3];
    *reinterpret_cast<ushort4*>(oB + pr*PSTO + t*RSTO + colbase) = pk;
  }
}

// ---------------- stage4 (K=192): k-outer / j-inner, swapped (r11) ----------------
__device__ __forceinline__ void mfma_stage4(const unsigned short* __restrict__ aB,
    const unsigned short* __restrict__ gW, unsigned short* __restrict__ oB,
    const float* __restrict__ gb0, const float* __restrict__ gb1,
    const float* __restrict__ gb2,
    const int Mtile0, const int Ntile, const int lm, const int lk)
{
  const unsigned short* wbase = gW + (Ntile*16 + lm)*192 + lk*8;
  const int colbase = Ntile*16 + lk*4;
  f32x4 aP[2], aQ[2], aR[2];
  {
    const f32x4 b0v = *reinterpret_cast<const f32x4*>(gb0 + colbase);
    const f32x4 b1v = *reinterpret_cast<const f32x4*>(gb1 + colbase);
    const f32x4 b2v = *reinterpret_cast<const f32x4*>(gb2 + colbase);
    #pragma unroll
    for (int j=0;j<2;++j){ aP[j]=b0v; aQ[j]=b1v; aR[j]=b2v; }
  }
  #pragma unroll 1
  for (int kb = 0; kb < 2; ++kb){
    bf16x8 wp[3], wq[3], wr[3];
    #pragma unroll
    for (int s = 0; s < 3; ++s){
      const int ks = kb*3 + s;
      wp[s] = *reinterpret_cast<const bf16x8*>(wbase +         ks*32);
      wq[s] = *reinterpret_cast<const bf16x8*>(wbase +  6144 + ks*32); // 32*192
      wr[s] = *reinterpret_cast<const bf16x8*>(wbase + 12288 + ks*32);
    }
    #pragma unroll
    for (int j = 0; j < 2; ++j){
      const int m  = (Mtile0 + j*4)*16 + lm;
      const int pr = m >> 2, t = m & 3;
      #pragma unroll
      for (int s = 0; s < 3; ++s){
        const int ks = kb*3 + s;
        const int elem = pr*432 + (t + (ks>>1))*72 + (ks&1)*32 + lk*8;
        const bf16x8 a = *reinterpret_cast<const bf16x8*>(aB + elem);
        aP[j] = __builtin_amdgcn_mfma_f32_16x16x32_bf16(wp[s], a, aP[j], 0,0,0);
        aQ[j] = __builtin_amdgcn_mfma_f32_16x16x32_bf16(wq[s], a, aQ[j], 0,0,0);
        aR[j] = __builtin_amdgcn_mfma_f32_16x16x32_bf16(wr[s], a, aR[j], 0,0,0);
      }
    }
  }
  #pragma unroll
  for (int j = 0; j < 2; ++j){
    const int m  = (Mtile0 + j*4)*16 + lm;
    const int pr = m >> 2, t = m & 3;
    ushort4 pk;
    unsigned short pv[4];
    #pragma unroll
    for (int r = 0; r < 4; ++r){
      const float sig = 1.f/(1.f + __expf(-aQ[j][r]));
      pv[r] = f2bf_fast(fmaxf(fmaf(aP[j][r], sig, aR[j][r]), 0.f));
    }
    pk.x = pv[0]; pk.y = pv[1]; pk.z = pv[2]; pk.w = pv[3];
    *reinterpret_cast<ushort4*>(oB + pr*160 + t*40 + colbase) = pk;
  }
}

// ---------------- main fused kernel ----------------
// LDS map (bf16 elems, one 24,064-elem arena = 48,128B):
//   bufA = smem[0..13823]      : s1c1 bounce strips [wid*640, 640) (dead after);
//                                sxb at [11008..13823]; then h2 (s3 out),
//                                h3c (c2 out), tail A-source.
//   bufB = smem[13824..24063]  : h1c (s1c1 out), h3 (s4 out),
//                                tail bounce strips [wid*416, 416).
// Barriers: x | s1c1 | s3 | s4 | c2 | tail  = 5 (r11: 8).
__global__ __launch_bounds__(NT, 4) void stgcn_main(const Params p,
    const unsigned short* __restrict__ W)
{
  __shared__ __align__(16) unsigned short smem[24064];   // 48,128 B
  unsigned short* const bufA = smem;            // 13824 elems
  unsigned short* const bufB = smem + 13824;    // 10240 elems
  unsigned short* const sxbA = bufA + 11008;    // 2816 elems (x tile)

  const int tid = threadIdx.x;
  const int l   = tid & 63;
  const int wid = tid >> 6;     // 0..7
  const int lm  = l & 15;
  const int lk  = l >> 4;
  const int n   = blockIdx.x >> 5;          // b-fastest: 32 consecutive blocks
  const int b0  = (blockIdx.x & 31) * NP;   // share one n (weights L2-hot)

  // ---- x tile -> sxbA (bufA tail). even 8B chunks = bf16(x), odd zeros ----
  for (int i = tid; i < NP*22; i += NT){
    const int pr = i / 22, c = i - pr*22;
    const int t  = c >> 1;
    unsigned short v0=0,v1=0,v2=0,v3=0;
    if (!(c & 1) && t < 10){
      const float4 xf = *reinterpret_cast<const float4*>(
          &p.x[(size_t)(((b0+pr)*10 + t)*113 + n)*4]);
      v0 = f2bf(xf.x); v1 = f2bf(xf.y); v2 = f2bf(xf.z); v3 = f2bf(xf.w);
    }
    ushort4 pk; pk.x=v0; pk.y=v1; pk.z=v2; pk.w=v3;
    *reinterpret_cast<ushort4*>(&sxbA[i*4]) = pk;
  }
  __syncthreads();   // [b1]

  // ---- s1+c1 fused per wave: 2 Mtiles, both Ntiles, private bounce ----
  {
    unsigned short* bw = bufA + wid*640;   // 16 rows x 40 elems
    bf16x8 bact[2];
    int prs[2], tss[2];
    #pragma unroll
    for (int mt = 0; mt < 2; ++mt){
      const int m = (wid*2+mt)*16 + lm;
      prs[mt] = m >> 3; tss[mt] = m & 7;
      bact[mt] = *reinterpret_cast<const bf16x8*>(
          sxbA + prs[mt]*88 + tss[mt]*8 + lk*8);
    }
    #pragma unroll 1
    for (int mt = 0; mt < 2; ++mt){
      // stage1 (gated, K padded 12->32): both Ntiles -> bounce
      #pragma unroll
      for (int Nt = 0; Nt < 2; ++Nt){
        const unsigned short* wb = W + OFF_S1B + (Nt*16+lm)*32 + lk*8;
        const bf16x8 wp = *reinterpret_cast<const bf16x8*>(wb);
        const bf16x8 wq = *reinterpret_cast<const bf16x8*>(wb + 1024);
        const bf16x8 wr = *reinterpret_cast<const bf16x8*>(wb + 2048);
        const int cb = Nt*16 + lk*4;
        f32x4 aP = *reinterpret_cast<const f32x4*>(p.abp + cb);
        f32x4 aQ = *reinterpret_cast<const f32x4*>(p.abq + cb);
        f32x4 aR = *reinterpret_cast<const f32x4*>(p.abr + cb);
        aP = __builtin_amdgcn_mfma_f32_16x16x32_bf16(wp, bact[mt], aP, 0,0,0);
        aQ = __builtin_amdgcn_mfma_f32_16x16x32_bf16(wq, bact[mt], aQ, 0,0,0);
        aR = __builtin_amdgcn_mfma_f32_16x16x32_bf16(wr, bact[mt], aR, 0,0,0);
        unsigned short pv[4];
        #pragma unroll
        for (int r = 0; r < 4; ++r){
          const float sig = 1.f/(1.f + __expf(-aQ[r]));
          pv[r] = f2bf_fast(fmaxf(fmaf(aP[r], sig, aR[r]), 0.f));
        }
        ushort4 pk; pk.x=pv[0]; pk.y=pv[1]; pk.z=pv[2]; pk.w=pv[3];
        *reinterpret_cast<ushort4*>(bw + lm*40 + cb) = pk;   // row lm, 32 ch
      }
      // cheb1 from private bounce (same-wave DS: in-order, no barrier)
      const bf16x8 bh = *reinterpret_cast<const bf16x8*>(bw + lm*40 + lk*8);
      #pragma unroll
      for (int Nt = 0; Nt < 2; ++Nt){
        const bf16x8 wc = *reinterpret_cast<const bf16x8*>(
            W + OFF_CHEB_A + (Nt*16+lm)*32 + lk*8);
        const int cb = Nt*16 + lk*4;
        f32x4 acc = *reinterpret_cast<const f32x4*>(p.acb + cb);
        acc = __builtin_amdgcn_mfma_f32_16x16x32_bf16(wc, bh, acc, 0,0,0);
        unsigned short pv[4];
        #pragma unroll
        for (int r = 0; r < 4; ++r) pv[r] = f2bf_fast(fmaxf(acc[r], 0.f));
        ushort4 pk; pk.x=pv[0]; pk.y=pv[1]; pk.z=pv[2]; pk.w=pv[3];
        *reinterpret_cast<ushort4*>(bufB + prs[mt]*320 + tss[mt]*40 + cb) = pk;
      }
    }
  }
  __syncthreads();   // [b2]

  // ---- s3: (8,32)->(6,64) gated + BN(a). M=192(12) N=64(4) K=96. B->A ----
  {
    const float bnsc = INV_STD * p.ag[n], bnbt = p.abeta[n];
    mfma_stage<6,32,64,3, 40,320, 72,432, 96, 2, 6,2, true>(
        bufB, W+OFF_A2, bufA, p.abp2, p.abq2, p.abr2, wid>>2, wid&3, lm, lk, bnsc, bnbt);
  }
  __syncthreads();   // [b3]

  // ---- s4: (6,64)->(4,32) gated. M=128(8) N=32(2) K=192. A->B ----
  mfma_stage4(bufA, W+OFF_B1, bufB, p.bbp, p.bbq, p.bbr, wid>>1, wid&1, lm, lk);
  __syncthreads();   // [b4]

  // ---- c2: M=128(8) N=32(2) K=32. B->A ----
  mfma_stage<4,32,32,1, 40,160, 40,160, 32, 0, 2,4, false>(
      bufB, W+OFF_CHEB_B, bufA, p.bcb, p.bcb, p.bcb, wid>>1, wid&1, lm, lk, 0.f, 0.f);
  __syncthreads();   // [b5]

  // ---- tail: s6 + mlp1 + mlp2 fused per wave (4 pairs each) ----
  {
    unsigned short* h4W  = bufB + wid*416;   // 4 pairs x 32 (flatten order)
    unsigned short* hidW = h4W + 128;        // 4 pairs x 72
    const int lmv = lm & 7;                  // s6 row clamp (8 valid rows)
    const int prL = lmv >> 1, t6 = lmv & 1;
    const int prG = wid*4 + prL;             // block-local pair

    // s6: gated conv + BN(b), CO=16, K=96 (CIN=32 indexing: (t6+ks)*40)
    {
      const unsigned short* wb = W + OFF_B2 + lm*96 + lk*8;
      bf16x8 wp[3], wq[3], wr[3];
      #pragma unroll
      for (int ks = 0; ks < 3; ++ks){
        wp[ks] = *reinterpret_cast<const bf16x8*>(wb +        ks*32);
        wq[ks] = *reinterpret_cast<const bf16x8*>(wb + 1536 + ks*32);
        wr[ks] = *reinterpret_cast<const bf16x8*>(wb + 3072 + ks*32);
      }
      const int cb = lk*4;
      f32x4 aP = *reinterpret_cast<const f32x4*>(p.bbp2 + cb);
      f32x4 aQ = *reinterpret_cast<const f32x4*>(p.bbq2 + cb);
      f32x4 aR = *reinterpret_cast<const f32x4*>(p.bbr2 + cb);
      #pragma unroll
      for (int ks = 0; ks < 3; ++ks){
        const int elem = prG*160 + (t6 + ks)*40 + lk*8;   // FIX (was stage1-style)
        const bf16x8 a = *reinterpret_cast<const bf16x8*>(bufA + elem);
        aP = __builtin_amdgcn_mfma_f32_16x16x32_bf16(wp[ks], a, aP, 0,0,0);
        aQ = __builtin_amdgcn_mfma_f32_16x16x32_bf16(wq[ks], a, aQ, 0,0,0);
        aR = __builtin_amdgcn_mfma_f32_16x16x32_bf16(wr[ks], a, aR, 0,0,0);
      }
      if (lm < 8){
        const float bns = INV_STD * p.bg[n], bnb = p.bbeta[n];
        unsigned short pv[4];
        #pragma unroll
        for (int r = 0; r < 4; ++r){
          const float sig = 1.f/(1.f + __expf(-aQ[r]));
          float v = fmaxf(fmaf(aP[r], sig, aR[r]), 0.f);
          v = fmaxf(fmaf(v, bns, bnb), 0.f);
          pv[r] = f2bf_fast(v);
        }
        ushort4 pk; pk.x=pv[0]; pk.y=pv[1]; pk.z=pv[2]; pk.w=pv[3];
        *reinterpret_cast<ushort4*>(h4W + prL*32 + t6*16 + cb) = pk;
      }
    }
    // mlp1: feat(32) -> hid(64). 4 pairs (cols lm<4), 4 Ntiles, per-n weights
    {
      const bf16x8 bh = *reinterpret_cast<const bf16x8*>(h4W + (lm&3)*32 + lk*8);
      #pragma unroll
      for (int Nt = 0; Nt < 4; ++Nt){
        const bf16x8 wf = *reinterpret_cast<const bf16x8*>(
            W + OFF_W1 + n*2048 + (Nt*16+lm)*32 + lk*8);
        const int cb = Nt*16 + lk*4;
        f32x4 acc = *reinterpret_cast<const f32x4*>(p.b1 + n*64 + cb);
        acc = __builtin_amdgcn_mfma_f32_16x16x32_bf16(wf, bh, acc, 0,0,0);
        if (lm < 4){
          unsigned short pv[4];
          #pragma unroll
          for (int r = 0; r < 4; ++r) pv[r] = f2bf_fast(fmaxf(acc[r], 0.f));
          ushort4 pk; pk.x=pv[0]; pk.y=pv[1]; pk.z=pv[2]; pk.w=pv[3];
          *reinterpret_cast<ushort4*>(hidW + lm*72 + cb) = pk;
        }
      }
    }
    // mlp2: hid(64) -> 3. cols lm<4 valid, rows o=lk*4+r -> lk==0, r<3
    {
      const unsigned short* WM2 = W + OFF_W2 + n*192;
      const int lmo = (lm < 3) ? lm : 0;
      f32x4 acc = bcast(0.f);
      if (lk == 0){ acc[0]=p.b2[n*3]; acc[1]=p.b2[n*3+1]; acc[2]=p.b2[n*3+2]; }
      #pragma unroll
      for (int ks = 0; ks < 2; ++ks){
        const bf16x8 aw = *reinterpret_cast<const bf16x8*>(WM2 + lmo*64 + ks*32 + lk*8);
        const bf16x8 bh = *reinterpret_cast<const bf16x8*>(hidW + (lm&3)*72 + ks*32 + lk*8);
        acc = __builtin_amdgcn_mfma_f32_16x16x32_bf16(aw, bh, acc, 0,0,0);
      }
      if (lk == 0 && lm < 4){
        const int b = b0 + wid*4 + lm;
        float* op = p.out + ((size_t)b*113 + n)*3;
        op[0] = acc[0]; op[1] = acc[1]; op[2] = acc[2];
      }
    }
  }
}

} // namespace

extern "C" void kernel_launch(void* const* d_in, const int* in_sizes, int n_in,
                              void* d_out, int out_size, void* d_ws, size_t ws_size,
                              hipStream_t stream) {
  (void)in_sizes; (void)n_in; (void)ws_size; (void)out_size;
  Params p;
  p.x     = (const float*)d_in[0];
  // d_in[1] = edge_index (unused: ChebConv K=1 keeps only the identity term)
  p.awp   = (const float*)d_in[2];  p.abp   = (const float*)d_in[3];
  p.awq   = (const float*)d_in[4];  p.abq   = (const float*)d_in[5];
  p.awr   = (const float*)d_in[6];  p.abr   = (const float*)d_in[7];
  p.acw   = (const float*)d_in[8];  p.acb   = (const float*)d_in[9];
  p.awp2  = (const float*)d_in[10]; p.abp2  = (const float*)d_in[11];
  p.awq2  = (const float*)d_in[12]; p.abq2  = (const float*)d_in[13];
  p.awr2  = (const float*)d_in[14]; p.abr2  = (const float*)d_in[15];
  p.ag    = (const float*)d_in[16]; p.abeta = (const float*)d_in[17];
  p.bwp   = (const float*)d_in[18]; p.bbp   = (const float*)d_in[19];
  p.bwq   = (const float*)d_in[20]; p.bbq   = (const float*)d_in[21];
  p.bwr   = (const float*)d_in[22]; p.bbr   = (const float*)d_in[23];
  p.bcw   = (const float*)d_in[24]; p.bcb   = (const float*)d_in[25];
  p.bwp2  = (const float*)d_in[26]; p.bbp2  = (const float*)d_in[27];
  p.bwq2  = (const float*)d_in[28]; p.bbq2  = (const float*)d_in[29];
  p.bwr2  = (const float*)d_in[30]; p.bbr2  = (const float*)d_in[31];
  p.bg    = (const float*)d_in[32]; p.bbeta = (const float*)d_in[33];
  p.w1    = (const float*)d_in[34]; p.b1    = (const float*)d_in[35];
  p.w2    = (const float*)d_in[36]; p.b2    = (const float*)d_in[37];
  p.out   = (float*)d_out;

  unsigned short* W = (unsigned short*)d_ws;   // needs 599,424 bytes

  // prep: 299,712 work items
  stgcn_prep<<<1171, 256, 0, stream>>>(p, W);

  const int tiles = 113 * 32;  // 3616, b fastest within each n
  stgcn_main<<<tiles, NT, 0, stream>>>(p, W);
}

// Round 19
// 138.955 us; speedup vs baseline: 2.1002x; 1.2702x over previous
//
#include <hip/hip_runtime.h>
#include <hip/hip_bf16.h>
#include <math.h>

// STGCN fused, round 19: REVERT to round-11 kernel (bench-verified 138.7us,
// the session best). r18's per-wave fusion (176us) traded 3 barriers for
// duplicated weight loads + half-idle MFMA lanes - net loss. Ten structural
// levers (occupancy, LDS, barriers, ILP, vmem BW, MFMA shape, streaming,
// privatization) all failed to beat this kernel; locking it back in.
// Structure: operand-swapped MFMA (weights=A, acts=B -> contiguous-co
// epilogue, ushort4 stores), global B-frags from prepped ws, 48,128B LDS
// (sxb aliased onto bufB), launch_bounds(512,6), stage3 RELOADB.

namespace {

constexpr int NT = 512;               // 8 waves
constexpr int NP = 32;                // (b,n) pairs per block (same n)
constexpr float INV_STD = 0.9999950000374997f; // 1/sqrt(1+1e-5)

typedef __attribute__((ext_vector_type(8))) short bf16x8;
typedef __attribute__((ext_vector_type(4))) float f32x4;

// d_ws layout (bf16 element offsets). All sections 16B-aligned (off%8==0).
constexpr int OFF_CHEB_A = 0;         // [32co][32k]
constexpr int OFF_CHEB_B = 1024;      // [32co][32k]
constexpr int OFF_A2     = 2048;      // P,Q,R x [64co][96k]
constexpr int OFF_B1     = 20480;     // P,Q,R x [32co][192k]
constexpr int OFF_B2     = 38912;     // P,Q,R x [16co][96k]
constexpr int OFF_S1B    = 43520;     // P,Q,R x [32co][32k] (zero-padded K)
constexpr int OFF_W1     = 46592;     // 113 x [64h][32k]
constexpr int OFF_W2     = 278016;    // 113 x [3o][64k]
// total ws bytes needed: (278016 + 21696) * 2 = 599,424

__device__ __forceinline__ unsigned short f2bf(float f){   // RNE f32->bf16 (prep)
  unsigned int u = __float_as_uint(f);
  u += 0x7fffu + ((u >> 16) & 1u);
  return (unsigned short)(u >> 16);
}
__device__ __forceinline__ unsigned short f2bf_fast(float f){  // native RNE
  return __bfloat16_as_ushort(__float2bfloat16(f));
}
__device__ __forceinline__ f32x4 bcast(float v){ f32x4 r; r[0]=v; r[1]=v; r[2]=v; r[3]=v; return r; }

struct Params {
  const float *x;
  const float *awp,*abp,*awq,*abq,*awr,*abr,*acw,*acb;
  const float *awp2,*abp2,*awq2,*abq2,*awr2,*abr2,*ag,*abeta;
  const float *bwp,*bbp,*bwq,*bbq,*bwr,*bbr,*bcw,*bcb;
  const float *bwp2,*bbp2,*bwq2,*bbq2,*bwr2,*bbr2,*bg,*bbeta;
  const float *w1,*b1,*w2,*b2;
  float *out;
};

// ---------------- prep: one-time weight transpose/convert into ws ----------------
__global__ void stgcn_prep(const Params p, unsigned short* __restrict__ W)
{
  int e = blockIdx.x*256 + threadIdx.x;
  if (e < 2048){                                    // cheb a/b [ci][co] -> [co][ci]
    const float* src = (e < 1024) ? p.acw : p.bcw;
    const int j = e & 1023, co = j >> 5, k = j & 31;
    W[e] = f2bf(src[k*32 + co]);
    return;
  }
  e -= 2048;
  if (e < 18432){                                   // a2: 3 x [64co][96k]
    const int mat = e / 6144, j = e % 6144, co = j / 96, k = j % 96;
    const float* src = mat==0 ? p.awp2 : (mat==1 ? p.awq2 : p.awr2);
    W[OFF_A2 + e] = f2bf(src[k*64 + co]);
    return;
  }
  e -= 18432;
  if (e < 18432){                                   // b1: 3 x [32co][192k]
    const int mat = e / 6144, j = e % 6144, co = j / 192, k = j % 192;
    const float* src = mat==0 ? p.bwp : (mat==1 ? p.bwq : p.bwr);
    W[OFF_B1 + e] = f2bf(src[k*32 + co]);
    return;
  }
  e -= 18432;
  if (e < 4608){                                    // b2: 3 x [16co][96k]
    const int mat = e / 1536, j = e % 1536, co = j / 96, k = j % 96;
    const float* src = mat==0 ? p.bwp2 : (mat==1 ? p.bwq2 : p.bwr2);
    W[OFF_B2 + e] = f2bf(src[k*16 + co]);
    return;
  }
  e -= 4608;
  if (e < 3072){                                    // s1: 3 x [32co][32k], k=tt*8+ci
    const int mat = e / 1024, j = e % 1024, co = j >> 5, k = j & 31;
    const int tt = k >> 3, ci = k & 7;
    const float* src = mat==0 ? p.awp : (mat==1 ? p.awq : p.awr);
    W[OFF_S1B + e] = (ci < 4 && tt < 3) ? f2bf(src[(tt*4+ci)*32 + co])
                                        : (unsigned short)0;
    return;
  }
  e -= 3072;
  if (e < 231424){ W[OFF_W1 + e] = f2bf(p.w1[e]); return; }  // [n][h][f] already B^T
  e -= 231424;
  if (e < 21696){ W[OFF_W2 + e] = f2bf(p.w2[e]); }           // [n][o][k] already B^T
}

// ---------------- generic MFMA stage (operand-swapped) ----------------
// Weights are the A operand (row = co = Ntile*16+lm), activations are B
// (col = m = Mtile*16+lm). Read addresses identical to the unswapped form.
// C: lane holds co = Ntile*16 + lk*4 + r (4 consecutive) for ONE m ->
// epilogue is a single ushort4 store + float4 bias init.
// EPI: 0 = relu(acc+bias); 1 = relu(P*sig(Q)+R); 2 = EPI1 then relu(v*bn+bt).
template<int TOUT, int CIN, int COUT, int NK, int RSTI, int PSTI, int RSTO, int PSTO,
         int KP, int EPI, int MJOBS, int MSTEP, bool RELOADB>
__device__ __forceinline__ void mfma_stage(const unsigned short* __restrict__ aB,
    const unsigned short* __restrict__ gW, unsigned short* __restrict__ oB,
    const float* __restrict__ gb0, const float* __restrict__ gb1,
    const float* __restrict__ gb2,
    const int Mtile0, const int Ntile, const int lm, const int lk,
    const float bnsc, const float bnbt)
{
  const unsigned short* wbase = gW + (Ntile*16 + lm)*KP + lk*8;
  const int colbase = Ntile*16 + lk*4;      // this lane's 4 output channels
  bf16x8 wp[NK], wq[NK], wr[NK];
  if constexpr (!RELOADB){
    #pragma unroll
    for (int ks = 0; ks < NK; ++ks){
      wp[ks] = *reinterpret_cast<const bf16x8*>(wbase + ks*32);
      if constexpr (EPI >= 1){
        wq[ks] = *reinterpret_cast<const bf16x8*>(wbase +   COUT*KP + ks*32);
        wr[ks] = *reinterpret_cast<const bf16x8*>(wbase + 2*COUT*KP + ks*32);
      }
    }
  }
  const f32x4 b0v = *reinterpret_cast<const f32x4*>(gb0 + colbase);
  f32x4 b1v, b2v;
  if constexpr (EPI >= 1){
    b1v = *reinterpret_cast<const f32x4*>(gb1 + colbase);
    b2v = *reinterpret_cast<const f32x4*>(gb2 + colbase);
  }

  #pragma unroll 1
  for (int j = 0; j < MJOBS; ++j){
    const int m  = (Mtile0 + j*MSTEP)*16 + lm;
    const int pr = m / TOUT;
    const int t  = m - pr*TOUT;
    f32x4 aP = b0v, aQ, aR;
    if constexpr (EPI >= 1){ aQ = b1v; aR = b2v; }
    #pragma unroll
    for (int ks = 0; ks < NK; ++ks){
      bf16x8 fp, fq, fr;
      if constexpr (RELOADB){
        fp = *reinterpret_cast<const bf16x8*>(wbase + ks*32);
        if constexpr (EPI >= 1){
          fq = *reinterpret_cast<const bf16x8*>(wbase +   COUT*KP + ks*32);
          fr = *reinterpret_cast<const bf16x8*>(wbase + 2*COUT*KP + ks*32);
        }
      } else {
        fp = wp[ks];
        if constexpr (EPI >= 1){ fq = wq[ks]; fr = wr[ks]; }
      }
      int elem;
      if constexpr (CIN == 32) elem = pr*PSTI + (t + ks)*RSTI + lk*8;
      else                     elem = pr*PSTI + (t + (ks>>1))*RSTI + (ks&1)*32 + lk*8;
      const bf16x8 a = *reinterpret_cast<const bf16x8*>(aB + elem);
      aP = __builtin_amdgcn_mfma_f32_16x16x32_bf16(fp, a, aP, 0, 0, 0);
      if constexpr (EPI >= 1){
        aQ = __builtin_amdgcn_mfma_f32_16x16x32_bf16(fq, a, aQ, 0, 0, 0);
        aR = __builtin_amdgcn_mfma_f32_16x16x32_bf16(fr, a, aR, 0, 0, 0);
      }
    }
    ushort4 pk;
    unsigned short pv[4];
    #pragma unroll
    for (int r = 0; r < 4; ++r){
      float v;
      if constexpr (EPI == 0) v = fmaxf(aP[r], 0.f);
      else {
        const float sig = 1.f/(1.f + __expf(-aQ[r]));
        v = fmaxf(fmaf(aP[r], sig, aR[r]), 0.f);
        if constexpr (EPI == 2) v = fmaxf(fmaf(v, bnsc, bnbt), 0.f);
      }
      pv[r] = f2bf_fast(v);
    }
    pk.x = pv[0]; pk.y = pv[1]; pk.z = pv[2]; pk.w = pv[3];
    *reinterpret_cast<ushort4*>(oB + pr*PSTO + t*RSTO + colbase) = pk;
  }
}

// ---------------- stage4 (K=192): k-outer / j-inner, swapped ----------------
__device__ __forceinline__ void mfma_stage4(const unsigned short* __restrict__ aB,
    const unsigned short* __restrict__ gW, unsigned short* __restrict__ oB,
    const float* __restrict__ gb0, const float* __restrict__ gb1,
    const float* __restrict__ gb2,
    const int Mtile0, const int Ntile, const int lm, const int lk)
{
  const unsigned short* wbase = gW + (Ntile*16 + lm)*192 + lk*8;
  const int colbase = Ntile*16 + lk*4;
  f32x4 aP[2], aQ[2], aR[2];
  {
    const f32x4 b0v = *reinterpret_cast<const f32x4*>(gb0 + colbase);
    const f32x4 b1v = *reinterpret_cast<const f32x4*>(gb1 + colbase);
    const f32x4 b2v = *reinterpret_cast<const f32x4*>(gb2 + colbase);
    #pragma unroll
    for (int j=0;j<2;++j){ aP[j]=b0v; aQ[j]=b1v; aR[j]=b2v; }
  }
  #pragma unroll 1
  for (int kb = 0; kb < 2; ++kb){
    bf16x8 wp[3], wq[3], wr[3];
    #pragma unroll
    for (int s = 0; s < 3; ++s){
      const int ks = kb*3 + s;
      wp[s] = *reinterpret_cast<const bf16x8*>(wbase +         ks*32);
      wq[s] = *reinterpret_cast<const bf16x8*>(wbase +  6144 + ks*32); // 32*192
      wr[s] = *reinterpret_cast<const bf16x8*>(wbase + 12288 + ks*32);
    }
    #pragma unroll
    for (int j = 0; j < 2; ++j){
      const int m  = (Mtile0 + j*4)*16 + lm;
      const int pr = m >> 2, t = m & 3;
      #pragma unroll
      for (int s = 0; s < 3; ++s){
        const int ks = kb*3 + s;
        const int elem = pr*432 + (t + (ks>>1))*72 + (ks&1)*32 + lk*8;
        const bf16x8 a = *reinterpret_cast<const bf16x8*>(aB + elem);
        aP[j] = __builtin_amdgcn_mfma_f32_16x16x32_bf16(wp[s], a, aP[j], 0,0,0);
        aQ[j] = __builtin_amdgcn_mfma_f32_16x16x32_bf16(wq[s], a, aQ[j], 0,0,0);
        aR[j] = __builtin_amdgcn_mfma_f32_16x16x32_bf16(wr[s], a, aR[j], 0,0,0);
      }
    }
  }
  #pragma unroll
  for (int j = 0; j < 2; ++j){
    const int m  = (Mtile0 + j*4)*16 + lm;
    const int pr = m >> 2, t = m & 3;
    ushort4 pk;
    unsigned short pv[4];
    #pragma unroll
    for (int r = 0; r < 4; ++r){
      const float sig = 1.f/(1.f + __expf(-aQ[j][r]));
      pv[r] = f2bf_fast(fmaxf(fmaf(aP[j][r], sig, aR[j][r]), 0.f));
    }
    pk.x = pv[0]; pk.y = pv[1]; pk.z = pv[2]; pk.w = pv[3];
    *reinterpret_cast<ushort4*>(oB + pr*160 + t*40 + colbase) = pk;
  }
}

// ---------------- main fused kernel ----------------
// LDS: one 48,128 B arena. bufA = smem[0..13823], bufB = smem[13824..24063],
// sxb ALIASES bufB (dead before cheb1 writes bufB).
// launch_bounds(512,6) + stage3 frag-reload + unroll-1 M loops (r10 codegen).
__global__ __launch_bounds__(NT, 6) void stgcn_main(const Params p,
    const unsigned short* __restrict__ W)
{
  __shared__ __align__(16) unsigned short smem[24064];   // 48,128 B
  unsigned short* const bufA = smem;            // 13824 elems (27648 B)
  unsigned short* const bufB = smem + 13824;    // 10240 elems (20480 B)
  unsigned short* const sxb  = bufB;            // 2816 elems, dead before cheb1

  const int tid = threadIdx.x;
  const int l   = tid & 63;
  const int wid = tid >> 6;     // 0..7
  const int lm  = l & 15;
  const int lk  = l >> 4;
  const int n   = blockIdx.x >> 5;          // b-fastest: 32 consecutive blocks
  const int b0  = (blockIdx.x & 31) * NP;   // share one n (weights L2-hot)

  // x tile: one 8B chunk per (pr, half-slot); even chunks get bf16(x), odd zeros
  for (int i = tid; i < NP*22; i += NT){
    const int pr = i / 22, c = i - pr*22;
    const int t  = c >> 1;
    unsigned short v0=0,v1=0,v2=0,v3=0;
    if (!(c & 1) && t < 10){
      const float4 xf = *reinterpret_cast<const float4*>(
          &p.x[(size_t)(((b0+pr)*10 + t)*113 + n)*4]);
      v0 = f2bf(xf.x); v1 = f2bf(xf.y); v2 = f2bf(xf.z); v3 = f2bf(xf.w);
    }
    ushort4 pk; pk.x=v0; pk.y=v1; pk.z=v2; pk.w=v3;
    *reinterpret_cast<ushort4*>(&sxb[i*4]) = pk;
  }
  __syncthreads();

  // stage1: (10,4)->(8,32) gated conv, K padded 12->32. M=256(16) N=32(2) -> bufA
  mfma_stage<8,32,32,1, 8,88, 40,320, 32, 1, 4,4, false>(
      sxb, W+OFF_S1B, bufA, p.abp, p.abq, p.abr, wid>>1, wid&1, lm, lk, 0.f, 0.f);
  __syncthreads();

  // cheb1: M=256(16) N=32(2) K=32 -> bufB (overwrites sxb region, now dead)
  mfma_stage<8,32,32,1, 40,320, 40,320, 32, 0, 4,4, false>(
      bufA, W+OFF_CHEB_A, bufB, p.acb, p.acb, p.acb, wid>>1, wid&1, lm, lk, 0.f, 0.f);
  __syncthreads();

  // stage3: (8,32)->(6,64) gated + BN(a). M=192(12) N=64(4) K=96 -> bufA
  {
    const float bnsc = INV_STD * p.ag[n], bnbt = p.abeta[n];
    mfma_stage<6,32,64,3, 40,320, 72,432, 96, 2, 6,2, true>(
        bufB, W+OFF_A2, bufA, p.abp2, p.abq2, p.abr2, wid>>2, wid&3, lm, lk, bnsc, bnbt);
  }
  __syncthreads();

  // stage4: (6,64)->(4,32) gated. M=128(8) N=32(2) K=192 -> bufB
  mfma_stage4(bufA, W+OFF_B1, bufB, p.bbp, p.bbq, p.bbr, wid>>1, wid&1, lm, lk);
  __syncthreads();

  // cheb2: M=128(8) N=32(2) K=32 -> bufA
  mfma_stage<4,32,32,1, 40,160, 40,160, 32, 0, 2,4, false>(
      bufB, W+OFF_CHEB_B, bufA, p.bcb, p.bcb, p.bcb, wid>>1, wid&1, lm, lk, 0.f, 0.f);
  __syncthreads();

  // stage6: (4,32)->(2,16) gated + BN(b). M=64(4) N=16(1) K=96 -> bufB (h4)
  if (wid < 4){
    const float bnsc = INV_STD * p.bg[n], bnbt = p.bbeta[n];
    mfma_stage<2,32,16,3, 40,160, 16,40, 96, 2, 1,1, false>(
        bufA, W+OFF_B2, bufB, p.bbp2, p.bbq2, p.bbr2, wid, 0, lm, lk, bnsc, bnbt);
  }
  __syncthreads();

  // mlp1: feat(32) -> hid(64). M=32(2) N=64(4) K=32 -> bufA
  mfma_stage<1,32,64,1, 16,40, 16,72, 32, 0, 1,1, false>(
      bufB, W+OFF_W1 + n*2048, bufA, p.b1 + n*64, p.b1, p.b1, wid&1, wid>>1, lm, lk, 0.f, 0.f);
  __syncthreads();

  // mlp2: hid(64) -> 3, swapped. C: row=o=lk*4+r, col=m=Mtile*16+lm.
  // Only lk==0, r<3 valid; each such lane stores 3 consecutive f32.
  if (wid < 2){
    const unsigned short* WM2 = W + OFF_W2 + n*192;
    const int Mtile = wid;
    const int m = Mtile*16 + lm;
    const int lmo = (lm < 3) ? lm : 0;       // clamp A-row into valid W2 rows
    f32x4 acc = bcast(0.f);
    if (lk == 0){ acc[0]=p.b2[n*3]; acc[1]=p.b2[n*3+1]; acc[2]=p.b2[n*3+2]; }
    #pragma unroll
    for (int ks = 0; ks < 2; ++ks){
      const bf16x8 aw = *reinterpret_cast<const bf16x8*>(WM2 + lmo*64 + ks*32 + lk*8);
      const bf16x8 bh = *reinterpret_cast<const bf16x8*>(bufA + m*72 + ks*32 + lk*8);
      acc = __builtin_amdgcn_mfma_f32_16x16x32_bf16(aw, bh, acc, 0, 0, 0);
    }
    if (lk == 0){
      float* op = p.out + (size_t)((b0 + m)*113 + n)*3;
      op[0] = acc[0]; op[1] = acc[1]; op[2] = acc[2];
    }
  }
}

} // namespace

extern "C" void kernel_launch(void* const* d_in, const int* in_sizes, int n_in,
                              void* d_out, int out_size, void* d_ws, size_t ws_size,
                              hipStream_t stream) {
  (void)in_sizes; (void)n_in; (void)ws_size; (void)out_size;
  Params p;
  p.x     = (const float*)d_in[0];
  // d_in[1] = edge_index (unused: ChebConv K=1 keeps only the identity term)
  p.awp   = (const float*)d_in[2];  p.abp   = (const float*)d_in[3];
  p.awq   = (const float*)d_in[4];  p.abq   = (const float*)d_in[5];
  p.awr   = (const float*)d_in[6];  p.abr   = (const float*)d_in[7];
  p.acw   = (const float*)d_in[8];  p.acb   = (const float*)d_in[9];
  p.awp2  = (const float*)d_in[10]; p.abp2  = (const float*)d_in[11];
  p.awq2  = (const float*)d_in[12]; p.abq2  = (const float*)d_in[13];
  p.awr2  = (const float*)d_in[14]; p.abr2  = (const float*)d_in[15];
  p.ag    = (const float*)d_in[16]; p.abeta = (const float*)d_in[17];
  p.bwp   = (const float*)d_in[18]; p.bbp   = (const float*)d_in[19];
  p.bwq   = (const float*)d_in[20]; p.bbq   = (const float*)d_in[21];
  p.bwr   = (const float*)d_in[22]; p.bbr   = (const float*)d_in[23];
  p.bcw   = (const float*)d_in[24]; p.bcb   = (const float*)d_in[25];
  p.bwp2  = (const float*)d_in[26]; p.bbp2  = (const float*)d_in[27];
  p.bwq2  = (const float*)d_in[28]; p.bbq2  = (const float*)d_in[29];
  p.bwr2  = (const float*)d_in[30]; p.bbr2  = (const float*)d_in[31];
  p.bg    = (const float*)d_in[32]; p.bbeta = (const float*)d_in[33];
  p.w1    = (const float*)d_in[34]; p.b1    = (const float*)d_in[35];
  p.w2    = (const float*)d_in[36]; p.b2    = (const float*)d_in[37];
  p.out   = (float*)d_out;

  unsigned short* W = (unsigned short*)d_ws;   // needs 599,424 bytes

  // prep: 299,712 work items
  stgcn_prep<<<1171, 256, 0, stream>>>(p, W);

  const int tiles = 113 * 32;  // 3616, b fastest within each n
  stgcn_main<<<tiles, NT, 0, stream>>>(p, W);
}